// Round 1
// baseline (965.225 us; speedup 1.0000x reference)
//
#include <hip/hip_runtime.h>
#include <math.h>

#define TN 2048
#define DN 1024

typedef __attribute__((ext_vector_type(8))) _Float16 half8;
typedef __attribute__((ext_vector_type(4))) _Float16 half4v;
typedef __attribute__((ext_vector_type(2))) _Float16 half2v;
typedef __attribute__((ext_vector_type(4))) float f32x4;

#define NEG_INF (-3.0e38f)

__device__ __forceinline__ f32x4 mfma16(half8 a, half8 b, f32x4 c) {
  return __builtin_amdgcn_mfma_f32_16x16x32_f16(a, b, c, 0, 0, 0);
}

// One block = one (batch, Q-tile pair {pr, 63-pr}). 8 waves, 512 threads.
// Flash attention with Q in registers, K staged in LDS (row-major swizzled for
// QK^T, transposed copy for PV), online softmax, fused novelty/gate/gelu epilogue.
__global__ __launch_bounds__(512, 2)
void fused_novelty_gate(const float* __restrict__ x,
                        const float* __restrict__ pla,
                        const float* __restrict__ pls,
                        float* __restrict__ out) {
  __shared__ _Float16 Krow[32][1024];   // [key][feat ^ ((key&7)<<3)]  64 KB
  __shared__ _Float16 Kt[1024][40];     // [feat][key], pad 40         80 KB
  __shared__ _Float16 Pq[32][40];       // P weights [q][key]          2.5 KB
  __shared__ float Sred[2][32][32];     // QK^T k-split partials       8 KB (reused as epilogue scratch)
  __shared__ float m_s[32], l_s[32], corr_s[32], gate_s[32];

  const int tid = threadIdx.x;
  const int w   = tid >> 6;        // wave 0..7
  const int l   = tid & 63;
  const int lr  = l & 15;
  const int lg  = l >> 4;
  const int ti  = w & 1;           // S row-tile
  const int tj  = (w >> 1) & 1;    // S col-tile
  const int kq  = w >> 2;          // k-half for QK^T

  const int b  = blockIdx.x >> 5;  // batch
  const int pr = blockIdx.x & 31;  // pair index

  const float alpha = log1pf(expf(pla[0]));   // softplus
  const float sigma = log1pf(expf(pls[0]));

  const float* xb = x + (size_t)b * TN * DN;
  float*       ob = out + (size_t)b * TN * DN;

  // staging assignment: thread -> (key row, feat chunk)
  const int skey = tid >> 4;          // 0..31
  const int sfo  = (tid & 15) * 4;    // feat base; +64*j

  for (int hv = 0; hv < 2; ++hv) {
    const int qt    = hv ? (63 - pr) : pr;
    const int qbase = qt * 32;
    const int nkt   = qt + 1;         // #key tiles (strictly-causal)

    // ---- Q tile -> f16 A-fragments in registers ----
    half8 qf[16];
    {
      const float* qp = xb + (size_t)(qbase + ti * 16 + lr) * DN + kq * 512 + lg * 8;
#pragma unroll
      for (int s = 0; s < 16; ++s) {
        float4 a = ((const float4*)(qp + s * 32))[0];
        float4 c = ((const float4*)(qp + s * 32))[1];
        half8 h;
        h[0]=(_Float16)a.x; h[1]=(_Float16)a.y; h[2]=(_Float16)a.z; h[3]=(_Float16)a.w;
        h[4]=(_Float16)c.x; h[5]=(_Float16)c.y; h[6]=(_Float16)c.z; h[7]=(_Float16)c.w;
        qf[s] = h;
      }
    }

    f32x4 oacc[2][8];
#pragma unroll
    for (int rt = 0; rt < 2; ++rt)
#pragma unroll
      for (int ct = 0; ct < 8; ++ct)
        oacc[rt][ct] = f32x4{0.f, 0.f, 0.f, 0.f};

    if (tid < 32) { m_s[tid] = NEG_INF; l_s[tid] = 0.0f; }

    // prologue: load K tile 0 into registers
    float4 pf[16];
    {
      const float* kp = xb + (size_t)skey * DN + sfo;
#pragma unroll
      for (int j = 0; j < 16; ++j)
        pf[j] = *(const float4*)(kp + 64 * j);
    }

    for (int kt = 0; kt < nkt; ++kt) {
      // ---- phase A: staged regs -> Krow (f16, swizzled) ----
      {
        const int swz = (skey & 7) << 3;
#pragma unroll
        for (int j = 0; j < 16; ++j) {
          half4v h;
          h[0]=(_Float16)pf[j].x; h[1]=(_Float16)pf[j].y;
          h[2]=(_Float16)pf[j].z; h[3]=(_Float16)pf[j].w;
          *(half4v*)&Krow[skey][(sfo + 64 * j) ^ swz] = h;
        }
      }
      __syncthreads();

      // ---- prefetch next K tile (latency hides under QK/softmax/PV) ----
      if (kt + 1 < nkt) {
        const float* kp = xb + (size_t)((kt + 1) * 32 + skey) * DN + sfo;
#pragma unroll
        for (int j = 0; j < 16; ++j)
          pf[j] = *(const float4*)(kp + 64 * j);
      }

      // ---- QK^T: each wave one 16x16 S tile over its k-half ----
      {
        f32x4 sacc = f32x4{0.f, 0.f, 0.f, 0.f};
        const int key  = tj * 16 + lr;
        const int kswz = (key & 7) << 3;
#pragma unroll
        for (int s = 0; s < 16; ++s) {
          half8 bf = *(const half8*)&Krow[key][(kq * 512 + s * 32 + lg * 8) ^ kswz];
          sacc = mfma16(qf[s], bf, sacc);
        }
#pragma unroll
        for (int j = 0; j < 4; ++j)
          Sred[kq][ti * 16 + lg * 4 + j][tj * 16 + lr] = sacc[j];
      }

      // ---- phase B: Krow -> Kt transpose (for PV key-contiguous B-frags) ----
      {
        const int kgi = tid & 3;
        const int fpb = tid >> 2;
#pragma unroll
        for (int j = 0; j < 4; ++j) {
          const int f = (fpb + 128 * j) * 2;
          half8 lo, hi;
#pragma unroll
          for (int k8 = 0; k8 < 8; ++k8) {
            const int key = kgi * 8 + k8;
            half2v v = *(const half2v*)&Krow[key][f ^ ((key & 7) << 3)];
            lo[k8] = v[0]; hi[k8] = v[1];
          }
          *(half8*)&Kt[f][kgi * 8]     = lo;
          *(half8*)&Kt[f + 1][kgi * 8] = hi;
        }
      }
      __syncthreads();

      // ---- online softmax: 16 lanes per row ----
      {
        const int r   = tid >> 4;
        const int c0  = tid & 15;
        const int qg  = qbase + r;
        const int kb0 = kt * 32;
        float s0 = (Sred[0][r][c0]      + Sred[1][r][c0])      * 0.03125f;
        float s1 = (Sred[0][r][c0 + 16] + Sred[1][r][c0 + 16]) * 0.03125f;
        const bool v0 = (kb0 + c0)      < qg;   // strictly past
        const bool v1 = (kb0 + c0 + 16) < qg;
        if (!v0) s0 = NEG_INF;
        if (!v1) s1 = NEG_INF;
        float tmax = fmaxf(s0, s1);
#pragma unroll
        for (int d = 1; d < 16; d <<= 1)
          tmax = fmaxf(tmax, __shfl_xor(tmax, d));
        const float m_old = m_s[r];
        const float m_new = fmaxf(m_old, tmax);
        float p0 = v0 ? __expf(s0 - m_new) : 0.0f;
        float p1 = v1 ? __expf(s1 - m_new) : 0.0f;
        float ps = p0 + p1;
#pragma unroll
        for (int d = 1; d < 16; d <<= 1)
          ps += __shfl_xor(ps, d);
        const float corr = (m_old > 0.5f * NEG_INF) ? __expf(m_old - m_new) : 0.0f;
        if (c0 == 0) {
          m_s[r]    = m_new;
          l_s[r]    = l_s[r] * corr + ps;
          corr_s[r] = corr;
        }
        Pq[r][c0]      = (_Float16)p0;
        Pq[r][c0 + 16] = (_Float16)p1;
      }
      __syncthreads();

      // ---- rescale O and PV ----
      {
#pragma unroll
        for (int rt = 0; rt < 2; ++rt)
#pragma unroll
          for (int j = 0; j < 4; ++j) {
            const float cr = corr_s[rt * 16 + lg * 4 + j];
#pragma unroll
            for (int ct = 0; ct < 8; ++ct)
              oacc[rt][ct][j] *= cr;
          }
        half8 a0 = *(const half8*)&Pq[lr][lg * 8];
        half8 a1 = *(const half8*)&Pq[16 + lr][lg * 8];
#pragma unroll
        for (int ct = 0; ct < 8; ++ct) {
          const int f = w * 128 + ct * 16 + lr;
          half8 bf = *(const half8*)&Kt[f][lg * 8];
          oacc[0][ct] = mfma16(a0, bf, oacc[0][ct]);
          oacc[1][ct] = mfma16(a1, bf, oacc[1][ct]);
        }
      }
      __syncthreads();
    }

    // ---- epilogue: per-row <x,O>, |x|^2, |O|^2 ----
    {
      float* ered = &Sred[0][0][0];   // reuse: [(row*8+w)*4 + {0,1,2}]
#pragma unroll
      for (int rt = 0; rt < 2; ++rt)
#pragma unroll
        for (int j = 0; j < 4; ++j) {
          const int row = rt * 16 + lg * 4 + j;
          const float* xr = xb + (size_t)(qbase + row) * DN + w * 128 + lr;
          float a1 = 0.f, a2 = 0.f, a3 = 0.f;
#pragma unroll
          for (int ct = 0; ct < 8; ++ct) {
            const float xv = xr[ct * 16];
            const float ov = oacc[rt][ct][j];
            a1 += xv * ov; a2 += xv * xv; a3 += ov * ov;
          }
#pragma unroll
          for (int d = 1; d < 16; d <<= 1) {
            a1 += __shfl_xor(a1, d);
            a2 += __shfl_xor(a2, d);
            a3 += __shfl_xor(a3, d);
          }
          if (lr == 0) {
            float* e = ered + (row * 8 + w) * 4;
            e[0] = a1; e[1] = a2; e[2] = a3;
          }
        }
    }
    __syncthreads();
    if (tid < 32) {
      const float* ered = &Sred[0][0][0];
      float SxO = 0.f, Sxx = 0.f, SOO = 0.f;
#pragma unroll
      for (int wv = 0; wv < 8; ++wv) {
        const float* e = ered + (tid * 8 + wv) * 4;
        SxO += e[0]; Sxx += e[1]; SOO += e[2];
      }
      const float lden = l_s[tid];
      float cosv = 0.0f;
      if (lden > 0.0f) {             // context = O/l ; l==0 -> context 0 -> cos 0
        const float nx = fmaxf(sqrtf(Sxx), 1e-12f);
        const float nc = fmaxf(sqrtf(SOO) / lden, 1e-12f);
        cosv = (SxO / lden) / (nx * nc);
      }
      float nov = fminf(fmaxf(1.0f - cosv, 0.0f), 2.0f) * 0.5f;
      gate_s[tid] = 1.0f + alpha * tanhf(sigma * nov);
    }
    __syncthreads();
    // ---- final: out = gelu_tanh(x * gate) ----
    {
#pragma unroll
      for (int rt = 0; rt < 2; ++rt)
#pragma unroll
        for (int j = 0; j < 4; ++j) {
          const int row = rt * 16 + lg * 4 + j;
          const float g = gate_s[row];
          const float* xr = xb + (size_t)(qbase + row) * DN + w * 128 + lr;
          float* orow     = ob + (size_t)(qbase + row) * DN + w * 128 + lr;
#pragma unroll
          for (int ct = 0; ct < 8; ++ct) {
            const float z = xr[ct * 16] * g;
            const float u = 0.7978845608028654f * (z + 0.044715f * z * z * z);
            orow[ct * 16] = 0.5f * z * (1.0f + tanhf(u));
          }
        }
    }
    __syncthreads();
  }
}

extern "C" void kernel_launch(void* const* d_in, const int* in_sizes, int n_in,
                              void* d_out, int out_size, void* d_ws, size_t ws_size,
                              hipStream_t stream) {
  const float* x  = (const float*)d_in[0];
  const float* la = (const float*)d_in[1];
  const float* ls = (const float*)d_in[2];
  float* out = (float*)d_out;
  fused_novelty_gate<<<dim3(256), dim3(512), 0, stream>>>(x, la, ls, out);
}

// Round 2
// 220.726 us; speedup vs baseline: 4.3730x; 4.3730x over previous
//
#include <hip/hip_runtime.h>
#include <math.h>

#define TN 2048
#define DN 1024
#define NEG_INF (-3.0e38f)

typedef __attribute__((ext_vector_type(8))) _Float16 half8;
typedef __attribute__((ext_vector_type(4))) _Float16 half4v;
typedef __attribute__((ext_vector_type(4))) float f32x4;

__device__ __forceinline__ f32x4 mfma16(half8 a, half8 b, f32x4 c) {
  return __builtin_amdgcn_mfma_f32_16x16x32_f16(a, b, c, 0, 0, 0);
}

// Tile image layout (32 keys x 1024 feats, f16, 64KB):
//   elem_off(key,f) = (f>>4)*512 + perm(key>>2)*64 + (key&3)*16 + (f&15)
//   perm(kg) = (kg&1)*4 + (kg>>1)   (so tr_read lane-group lg sees keys 8*lg+j)
// Subtile = 4 keys x 16 feats row-major (128B) -> ds_read_b64_tr_b16 compatible.
__device__ __forceinline__ int img_off(int key, int f) {
  const int kg = key >> 2;
  const int p  = ((kg & 1) << 2) | (kg >> 1);
  return (f >> 4) * 512 + p * 64 + (key & 3) * 16 + (f & 15);
}

// x fp32 [8][2048][1024] -> f16 tile images in ws: [b*64+tile][32768 elems]
__global__ __launch_bounds__(256) void convert_x(const float* __restrict__ x,
                                                 _Float16* __restrict__ w) {
  const long long gid = (long long)blockIdx.x * 256 + threadIdx.x;
  const long long e   = gid * 8;                 // image element index
  const int bt   = (int)(e >> 15);               // b*64 + tile
  const int et   = (int)(e & 32767);
  const int f16b = et >> 9;
  const int p    = (et >> 6) & 7;
  const int row  = (et >> 4) & 3;
  const int col0 = et & 15;                      // 0 or 8
  const int kg   = ((p & 3) << 1) | (p >> 2);    // inverse perm
  const int key  = kg * 4 + row;
  const size_t xoff = ((size_t)bt * 32 + key) * DN + f16b * 16 + col0;
  float4 u0 = *(const float4*)(x + xoff);
  float4 u1 = *(const float4*)(x + xoff + 4);
  half8 h = {(_Float16)u0.x, (_Float16)u0.y, (_Float16)u0.z, (_Float16)u0.w,
             (_Float16)u1.x, (_Float16)u1.y, (_Float16)u1.z, (_Float16)u1.w};
  *(half8*)(w + e) = h;
}

template <bool WS>
__global__ __launch_bounds__(512, 2)
void attn_gate(const float* __restrict__ x, const _Float16* __restrict__ wsx,
               const float* __restrict__ pla, const float* __restrict__ pls,
               float* __restrict__ out) {
  __shared__ _Float16 Kbuf[2][32768];     // double-buffered K tile images 128KB
  __shared__ float Sred[2][32][33];       // QK k-split partials (padded) 8.25KB
  __shared__ _Float16 Pq[32][40];         // P weights, padded rows      2.5KB
  __shared__ float m_s[32], l_s[32], corr_s[32], gate_s[32];

  const int tid = threadIdx.x;
  const int w   = tid >> 6;       // wave 0..7
  const int l   = tid & 63;
  const int lr  = l & 15;
  const int lg  = l >> 4;
  const int ti  = w & 1;          // S row-tile
  const int tj  = (w >> 1) & 1;   // S col-tile
  const int kq  = w >> 2;         // k-half for QK^T

  const int b  = blockIdx.x & 7;  // batch -> XCD (L2 locality on ws images)
  const int pr = blockIdx.x >> 3; // pair index 0..31

  const float alpha = log1pf(expf(pla[0]));
  const float sigma = log1pf(expf(pls[0]));

  const float* xb = x + (size_t)b * TN * DN;
  float*       ob = out + (size_t)b * TN * DN;

  for (int hv = 0; hv < 2; ++hv) {
    const int qt    = hv ? (63 - pr) : pr;
    const int qbase = qt * 32;
    const int nkt   = qt + 1;

    // ---- stage tiles 0 (and 1) ----
    if constexpr (WS) {
      const _Float16* t0 = wsx + (size_t)(b * 64 + 0) * 32768;
#pragma unroll
      for (int i = 0; i < 8; ++i)
        __builtin_amdgcn_global_load_lds(
            (const __attribute__((address_space(1))) void*)(t0 + w * 4096 + i * 512 + l * 8),
            (__attribute__((address_space(3))) void*)(&Kbuf[0][w * 4096 + i * 512]), 16, 0, 0);
      if (nkt > 1) {
        const _Float16* t1 = wsx + (size_t)(b * 64 + 1) * 32768;
#pragma unroll
        for (int i = 0; i < 8; ++i)
          __builtin_amdgcn_global_load_lds(
              (const __attribute__((address_space(1))) void*)(t1 + w * 4096 + i * 512 + l * 8),
              (__attribute__((address_space(3))) void*)(&Kbuf[1][w * 4096 + i * 512]), 16, 0, 0);
      }
    } else {
      const int skey = tid >> 4, sc = tid & 15;
      for (int t = 0; t < (nkt > 1 ? 2 : 1); ++t) {
        const float* kp = xb + (size_t)(t * 32 + skey) * DN + sc * 4;
#pragma unroll
        for (int j = 0; j < 16; ++j) {
          const int f = sc * 4 + 64 * j;
          float4 v = *(const float4*)(kp + 64 * j);
          half4v h = {(_Float16)v.x, (_Float16)v.y, (_Float16)v.z, (_Float16)v.w};
          *(half4v*)&Kbuf[t][img_off(skey, f)] = h;
        }
      }
    }

    // ---- Q fragments -> registers ----
    half8 qf[16];
    if constexpr (WS) {
      const _Float16* qtile = wsx + (size_t)(b * 64 + qt) * 32768;
      const int qrow = ti * 16 + lr;
      const int qkg  = qrow >> 2;
      const int qp   = (((qkg & 1) << 2) | (qkg >> 1)) * 64 + (qrow & 3) * 16 + (lg & 1) * 8;
#pragma unroll
      for (int s = 0; s < 16; ++s)
        qf[s] = *(const half8*)&qtile[(kq * 32 + s * 2 + (lg >> 1)) * 512 + qp];
    } else {
      const float* qp = xb + (size_t)(qbase + ti * 16 + lr) * DN + kq * 512 + lg * 8;
#pragma unroll
      for (int s = 0; s < 16; ++s) {
        float4 a = ((const float4*)(qp + s * 32))[0];
        float4 c = ((const float4*)(qp + s * 32))[1];
        half8 h;
        h[0]=(_Float16)a.x; h[1]=(_Float16)a.y; h[2]=(_Float16)a.z; h[3]=(_Float16)a.w;
        h[4]=(_Float16)c.x; h[5]=(_Float16)c.y; h[6]=(_Float16)c.z; h[7]=(_Float16)c.w;
        qf[s] = h;
      }
    }

    f32x4 oacc[2][8];
#pragma unroll
    for (int rt = 0; rt < 2; ++rt)
#pragma unroll
      for (int ct = 0; ct < 8; ++ct)
        oacc[rt][ct] = f32x4{0.f, 0.f, 0.f, 0.f};

    if (tid < 32) { m_s[tid] = NEG_INF; l_s[tid] = 0.0f; }
    __syncthreads();   // drains staging loads for tiles 0/1

    for (int kt = 0; kt < nkt; ++kt) {
      const int cur = kt & 1;

      // ---- QK^T: wave (ti,tj,kq) does a 16x16 S-tile over its k-half ----
      {
        f32x4 sacc = f32x4{0.f, 0.f, 0.f, 0.f};
        const int kg  = tj * 4 + (lr >> 2);
        const int kgp = ((kg & 1) << 2) | (kg >> 1);
        const int bk  = kgp * 64 + (lr & 3) * 16 + (lg & 1) * 8;
        const _Float16* kb = &Kbuf[cur][0];
#pragma unroll
        for (int s = 0; s < 16; ++s) {
          half8 bf = *(const half8*)&kb[(kq * 32 + s * 2 + (lg >> 1)) * 512 + bk];
          sacc = mfma16(qf[s], bf, sacc);
        }
#pragma unroll
        for (int j = 0; j < 4; ++j)
          Sred[kq][ti * 16 + lg * 4 + j][tj * 16 + lr] = sacc[j];
      }
      __syncthreads();   // (A) Sred ready

      // ---- online softmax: 16 lanes per q-row ----
      {
        const int r   = tid >> 4;
        const int c0  = tid & 15;
        const int qg  = qbase + r;
        const int kb0 = kt * 32;
        float s0 = (Sred[0][r][c0]      + Sred[1][r][c0])      * 0.03125f;
        float s1 = (Sred[0][r][c0 + 16] + Sred[1][r][c0 + 16]) * 0.03125f;
        const bool v0 = (kb0 + c0)      < qg;
        const bool v1 = (kb0 + c0 + 16) < qg;
        if (!v0) s0 = NEG_INF;
        if (!v1) s1 = NEG_INF;
        float tmax = fmaxf(s0, s1);
#pragma unroll
        for (int d = 1; d < 16; d <<= 1) tmax = fmaxf(tmax, __shfl_xor(tmax, d));
        const float m_old = m_s[r];
        const float m_new = fmaxf(m_old, tmax);
        float p0 = v0 ? __expf(s0 - m_new) : 0.0f;
        float p1 = v1 ? __expf(s1 - m_new) : 0.0f;
        float ps = p0 + p1;
#pragma unroll
        for (int d = 1; d < 16; d <<= 1) ps += __shfl_xor(ps, d);
        const float corr = (m_old > 0.5f * NEG_INF) ? __expf(m_old - m_new) : 0.0f;
        if (c0 == 0) {
          m_s[r]    = m_new;
          l_s[r]    = l_s[r] * corr + ps;
          corr_s[r] = corr;
        }
        Pq[r][c0]      = (_Float16)p0;
        Pq[r][c0 + 16] = (_Float16)p1;
      }
      __syncthreads();   // (B) Pq/corr ready

      // ---- PV: rescale O, then 16 MFMA with tr_read B-frags ----
      {
#pragma unroll
        for (int rt = 0; rt < 2; ++rt)
#pragma unroll
          for (int j = 0; j < 4; ++j) {
            const float cr = corr_s[rt * 16 + lg * 4 + j];
#pragma unroll
            for (int ct = 0; ct < 8; ++ct) oacc[rt][ct][j] *= cr;
          }
        half8 a0 = *(const half8*)&Pq[lr][lg * 8];
        half8 a1 = *(const half8*)&Pq[16 + lr][lg * 8];
        half4v lo[8], hi[8];
        const uint32_t ab =
            (uint32_t)(uintptr_t)(void*)&Kbuf[cur][w * 4096 + l * 4];  // +l*8 bytes
#define TRRD(CT, O0, O1)                                                      \
        asm volatile("ds_read_b64_tr_b16 %0, %2 offset:" O0 "\n\t"            \
                     "ds_read_b64_tr_b16 %1, %2 offset:" O1                   \
                     : "=v"(lo[CT]), "=v"(hi[CT]) : "v"(ab));
        TRRD(0, "0",    "512")  TRRD(1, "1024", "1536")
        TRRD(2, "2048", "2560") TRRD(3, "3072", "3584")
        TRRD(4, "4096", "4608") TRRD(5, "5120", "5632")
        TRRD(6, "6144", "6656") TRRD(7, "7168", "7680")
#undef TRRD
        asm volatile("s_waitcnt lgkmcnt(0)" ::: "memory");
        __builtin_amdgcn_sched_barrier(0);
#pragma unroll
        for (int ct = 0; ct < 8; ++ct) {
          half8 bf = __builtin_shufflevector(lo[ct], hi[ct], 0, 1, 2, 3, 4, 5, 6, 7);
          oacc[0][ct] = mfma16(a0, bf, oacc[0][ct]);
          oacc[1][ct] = mfma16(a1, bf, oacc[1][ct]);
        }
      }
      __syncthreads();   // (C) Kbuf[cur] free

      // ---- issue/stage tile kt+2 into buf[cur] ----
      if (kt + 2 < nkt) {
        if constexpr (WS) {
          const _Float16* tn = wsx + (size_t)(b * 64 + kt + 2) * 32768;
#pragma unroll
          for (int i = 0; i < 8; ++i)
            __builtin_amdgcn_global_load_lds(
                (const __attribute__((address_space(1))) void*)(tn + w * 4096 + i * 512 + l * 8),
                (__attribute__((address_space(3))) void*)(&Kbuf[cur][w * 4096 + i * 512]), 16, 0, 0);
        } else {
          const int skey = tid >> 4, sc = tid & 15;
          const float* kp = xb + (size_t)((kt + 2) * 32 + skey) * DN + sc * 4;
#pragma unroll
          for (int j = 0; j < 16; ++j) {
            const int f = sc * 4 + 64 * j;
            float4 v = *(const float4*)(kp + 64 * j);
            half4v h = {(_Float16)v.x, (_Float16)v.y, (_Float16)v.z, (_Float16)v.w};
            *(half4v*)&Kbuf[cur][img_off(skey, f)] = h;
          }
        }
      }
    }

    // ---- epilogue: per-row <x,O>, |x|^2, |O|^2 ----
    {
      float* ered = &Sred[0][0][0];
#pragma unroll
      for (int rt = 0; rt < 2; ++rt)
#pragma unroll
        for (int j = 0; j < 4; ++j) {
          const int row = rt * 16 + lg * 4 + j;
          const float* xr = xb + (size_t)(qbase + row) * DN + w * 128 + lr;
          float a1 = 0.f, a2 = 0.f, a3 = 0.f;
#pragma unroll
          for (int ct = 0; ct < 8; ++ct) {
            const float xv = xr[ct * 16];
            const float ov = oacc[rt][ct][j];
            a1 += xv * ov; a2 += xv * xv; a3 += ov * ov;
          }
#pragma unroll
          for (int d = 1; d < 16; d <<= 1) {
            a1 += __shfl_xor(a1, d);
            a2 += __shfl_xor(a2, d);
            a3 += __shfl_xor(a3, d);
          }
          if (lr == 0) {
            float* e = ered + (row * 8 + w) * 4;
            e[0] = a1; e[1] = a2; e[2] = a3;
          }
        }
    }
    __syncthreads();
    if (tid < 32) {
      const float* ered = &Sred[0][0][0];
      float SxO = 0.f, Sxx = 0.f, SOO = 0.f;
#pragma unroll
      for (int wv = 0; wv < 8; ++wv) {
        const float* e = ered + (tid * 8 + wv) * 4;
        SxO += e[0]; Sxx += e[1]; SOO += e[2];
      }
      const float lden = l_s[tid];
      float cosv = 0.0f;
      if (lden > 0.0f) {
        const float nx = fmaxf(sqrtf(Sxx), 1e-12f);
        const float nc = fmaxf(sqrtf(SOO) / lden, 1e-12f);
        cosv = (SxO / lden) / (nx * nc);
      }
      float nov = fminf(fmaxf(1.0f - cosv, 0.0f), 2.0f) * 0.5f;
      gate_s[tid] = 1.0f + alpha * tanhf(sigma * nov);
    }
    __syncthreads();
    {
#pragma unroll
      for (int rt = 0; rt < 2; ++rt)
#pragma unroll
        for (int j = 0; j < 4; ++j) {
          const int row = rt * 16 + lg * 4 + j;
          const float g = gate_s[row];
          const float* xr = xb + (size_t)(qbase + row) * DN + w * 128 + lr;
          float* orow     = ob + (size_t)(qbase + row) * DN + w * 128 + lr;
#pragma unroll
          for (int ct = 0; ct < 8; ++ct) {
            const float z = xr[ct * 16] * g;
            const float u = 0.7978845608028654f * (z + 0.044715f * z * z * z);
            orow[ct * 16] = 0.5f * z * (1.0f + tanhf(u));
          }
        }
    }
    __syncthreads();
  }
}

extern "C" void kernel_launch(void* const* d_in, const int* in_sizes, int n_in,
                              void* d_out, int out_size, void* d_ws, size_t ws_size,
                              hipStream_t stream) {
  const float* x  = (const float*)d_in[0];
  const float* la = (const float*)d_in[1];
  const float* ls = (const float*)d_in[2];
  float* out = (float*)d_out;
  const size_t need = (size_t)8 * 64 * 32768 * 2;   // 32 MB f16 tile images
  if (ws_size >= need) {
    convert_x<<<dim3(8192), dim3(256), 0, stream>>>(x, (_Float16*)d_ws);
    attn_gate<true><<<dim3(256), dim3(512), 0, stream>>>(
        x, (const _Float16*)d_ws, la, ls, out);
  } else {
    attn_gate<false><<<dim3(256), dim3(512), 0, stream>>>(
        x, (const _Float16*)nullptr, la, ls, out);
  }
}

// Round 3
// 196.472 us; speedup vs baseline: 4.9128x; 1.1234x over previous
//
#include <hip/hip_runtime.h>
#include <math.h>

#define TN 2048
#define DN 1024
#define NEG_INF (-3.0e38f)

typedef __attribute__((ext_vector_type(8))) _Float16 half8;
typedef __attribute__((ext_vector_type(4))) _Float16 half4v;
typedef __attribute__((ext_vector_type(4))) float f32x4;

__device__ __forceinline__ f32x4 mfma16(half8 a, half8 b, f32x4 c) {
  return __builtin_amdgcn_mfma_f32_16x16x32_f16(a, b, c, 0, 0, 0);
}

// lgkmcnt-only barrier: does NOT drain vmcnt, so in-flight global_load_lds
// staging survives across it (drained once per iter at the __syncthreads C).
#define BAR_LDS() asm volatile("s_waitcnt lgkmcnt(0)\ns_barrier" ::: "memory")

// Tile image layout (32 keys x 1024 feats, f16, 64KB):
//   elem_off(key,f) = (f>>4)*512 + perm(key>>2)*64 + (key&3)*16 + (f&15)
//   perm(kg) = (kg&1)*4 + (kg>>1)   (tr_read lane-group lg sees keys 8*lg+j)
__device__ __forceinline__ int img_off(int key, int f) {
  const int kg = key >> 2;
  const int p  = ((kg & 1) << 2) | (kg >> 1);
  return (f >> 4) * 512 + p * 64 + (key & 3) * 16 + (f & 15);
}

// x fp32 [8][2048][1024] -> f16 tile images in ws: [b*64+tile][32768 elems]
__global__ __launch_bounds__(256) void convert_x(const float* __restrict__ x,
                                                 _Float16* __restrict__ w) {
  const long long gid = (long long)blockIdx.x * 256 + threadIdx.x;
  const long long e   = gid * 8;
  const int bt   = (int)(e >> 15);
  const int et   = (int)(e & 32767);
  const int f16b = et >> 9;
  const int p    = (et >> 6) & 7;
  const int row  = (et >> 4) & 3;
  const int col0 = et & 15;
  const int kg   = ((p & 3) << 1) | (p >> 2);    // inverse perm
  const int key  = kg * 4 + row;
  const size_t xoff = ((size_t)bt * 32 + key) * DN + f16b * 16 + col0;
  float4 u0 = *(const float4*)(x + xoff);
  float4 u1 = *(const float4*)(x + xoff + 4);
  half8 h = {(_Float16)u0.x, (_Float16)u0.y, (_Float16)u0.z, (_Float16)u0.w,
             (_Float16)u1.x, (_Float16)u1.y, (_Float16)u1.z, (_Float16)u1.w};
  *(half8*)(w + e) = h;
}

template <bool WS>
__global__ __launch_bounds__(512)          // no min-waves: LDS caps occupancy,
void attn_gate(const float* __restrict__ x, const _Float16* __restrict__ wsx,
               const float* __restrict__ pla, const float* __restrict__ pls,
               float* __restrict__ out) {  // let VGPRs grow to avoid spills
  __shared__ _Float16 Kbuf[2][32768];     // double-buffered K tile images 128KB
  __shared__ float Sred[4][32][34];       // QK 4-way k-split partials  17.4KB
  __shared__ _Float16 Pq[32][40];
  __shared__ float m_s[32], l_s[32], corr_s[32], gate_s[32];

  const int tid = threadIdx.x;
  const int w   = tid >> 6;       // wave 0..7
  const int l   = tid & 63;
  const int lr  = l & 15;
  const int lg  = l >> 4;
  const int kq  = w & 3;          // k-quarter (256 feats) for QK^T
  const int ti  = w >> 2;         // S row-tile

  const int b  = blockIdx.x & 7;  // batch -> XCD (L2 locality)
  const int pr = blockIdx.x >> 3;

  const float alpha = log1pf(expf(pla[0]));
  const float sigma = log1pf(expf(pls[0]));

  const float* xb = x + (size_t)b * TN * DN;
  float*       ob = out + (size_t)b * TN * DN;

  for (int hv = 0; hv < 2; ++hv) {
    const int qt    = hv ? (63 - pr) : pr;
    const int qbase = qt * 32;
    const int nkt   = qt + 1;

    // ---- stage tiles 0 (and 1) ----
    if constexpr (WS) {
      const _Float16* t0 = wsx + (size_t)(b * 64 + 0) * 32768;
#pragma unroll
      for (int i = 0; i < 8; ++i)
        __builtin_amdgcn_global_load_lds(
            (const __attribute__((address_space(1))) void*)(t0 + w * 4096 + i * 512 + l * 8),
            (__attribute__((address_space(3))) void*)(&Kbuf[0][w * 4096 + i * 512]), 16, 0, 0);
      if (nkt > 1) {
        const _Float16* t1 = wsx + (size_t)(b * 64 + 1) * 32768;
#pragma unroll
        for (int i = 0; i < 8; ++i)
          __builtin_amdgcn_global_load_lds(
              (const __attribute__((address_space(1))) void*)(t1 + w * 4096 + i * 512 + l * 8),
              (__attribute__((address_space(3))) void*)(&Kbuf[1][w * 4096 + i * 512]), 16, 0, 0);
      }
    } else {
      const int skey = tid >> 4, sc = tid & 15;
      for (int t = 0; t < (nkt > 1 ? 2 : 1); ++t) {
        const float* kp = xb + (size_t)(t * 32 + skey) * DN + sc * 4;
#pragma unroll
        for (int j = 0; j < 16; ++j) {
          const int f = sc * 4 + 64 * j;
          float4 v = *(const float4*)(kp + 64 * j);
          half4v h = {(_Float16)v.x, (_Float16)v.y, (_Float16)v.z, (_Float16)v.w};
          *(half4v*)&Kbuf[t][img_off(skey, f)] = h;
        }
      }
    }

    // ---- Q fragments (k-quarter only: 8 x half8 = 32 VGPR) ----
    half8 qf[8];
    if constexpr (WS) {
      const _Float16* qtile = wsx + (size_t)(b * 64 + qt) * 32768;
      const int qrow = ti * 16 + lr;
      const int qkg  = qrow >> 2;
      const int qp   = (((qkg & 1) << 2) | (qkg >> 1)) * 64 + (qrow & 3) * 16 + (lg & 1) * 8;
#pragma unroll
      for (int s = 0; s < 8; ++s)
        qf[s] = *(const half8*)&qtile[(kq * 16 + s * 2 + (lg >> 1)) * 512 + qp];
    } else {
      const float* qp = xb + (size_t)(qbase + ti * 16 + lr) * DN + kq * 256 + lg * 8;
#pragma unroll
      for (int s = 0; s < 8; ++s) {
        float4 a = ((const float4*)(qp + s * 32))[0];
        float4 c = ((const float4*)(qp + s * 32))[1];
        half8 h;
        h[0]=(_Float16)a.x; h[1]=(_Float16)a.y; h[2]=(_Float16)a.z; h[3]=(_Float16)a.w;
        h[4]=(_Float16)c.x; h[5]=(_Float16)c.y; h[6]=(_Float16)c.z; h[7]=(_Float16)c.w;
        qf[s] = h;
      }
    }

    f32x4 oacc[2][8];
#pragma unroll
    for (int rt = 0; rt < 2; ++rt)
#pragma unroll
      for (int ct = 0; ct < 8; ++ct)
        oacc[rt][ct] = f32x4{0.f, 0.f, 0.f, 0.f};

    if (tid < 32) { m_s[tid] = NEG_INF; l_s[tid] = 0.0f; }
    __syncthreads();   // full drain: tiles 0/1 staged

    // QK B-frag bases (loop-invariant): keys lr (tj=0) and 16+lr (tj=1)
    const int kg0  = lr >> 2;
    const int bk0  = ((((kg0 & 1) << 2) | (kg0 >> 1)) << 6) + (lr & 3) * 16 + (lg & 1) * 8;
    const int kg1  = 4 + (lr >> 2);
    const int bk1  = ((((kg1 & 1) << 2) | (kg1 >> 1)) << 6) + (lr & 3) * 16 + (lg & 1) * 8;

    for (int kt = 0; kt < nkt; ++kt) {
      const int cur = kt & 1;

      // ---- QK^T: wave (ti,kq) -> both 16x16 S-tiles over its k-quarter ----
      {
        f32x4 s0 = f32x4{0.f, 0.f, 0.f, 0.f};
        f32x4 s1 = f32x4{0.f, 0.f, 0.f, 0.f};
        const _Float16* kb = &Kbuf[cur][0];
#pragma unroll
        for (int s = 0; s < 8; ++s) {
          const int base = (kq * 16 + s * 2 + (lg >> 1)) * 512;
          half8 bf0 = *(const half8*)&kb[base + bk0];
          half8 bf1 = *(const half8*)&kb[base + bk1];
          s0 = mfma16(qf[s], bf0, s0);
          s1 = mfma16(qf[s], bf1, s1);
        }
#pragma unroll
        for (int j = 0; j < 4; ++j) {
          Sred[kq][ti * 16 + lg * 4 + j][lr]      = s0[j];
          Sred[kq][ti * 16 + lg * 4 + j][16 + lr] = s1[j];
        }
      }
      BAR_LDS();   // (A) Sred ready — vmcnt NOT drained

      // ---- online softmax: 16 lanes per q-row ----
      {
        const int r   = tid >> 4;
        const int c0  = tid & 15;
        const int qg  = qbase + r;
        const int kb0 = kt * 32;
        float s0 = (Sred[0][r][c0] + Sred[1][r][c0] +
                    Sred[2][r][c0] + Sred[3][r][c0]) * 0.03125f;
        float s1 = (Sred[0][r][c0 + 16] + Sred[1][r][c0 + 16] +
                    Sred[2][r][c0 + 16] + Sred[3][r][c0 + 16]) * 0.03125f;
        const bool v0 = (kb0 + c0)      < qg;
        const bool v1 = (kb0 + c0 + 16) < qg;
        if (!v0) s0 = NEG_INF;
        if (!v1) s1 = NEG_INF;
        float tmax = fmaxf(s0, s1);
#pragma unroll
        for (int d = 1; d < 16; d <<= 1) tmax = fmaxf(tmax, __shfl_xor(tmax, d));
        const float m_old = m_s[r];
        const float m_new = fmaxf(m_old, tmax);
        float p0 = v0 ? __expf(s0 - m_new) : 0.0f;
        float p1 = v1 ? __expf(s1 - m_new) : 0.0f;
        float ps = p0 + p1;
#pragma unroll
        for (int d = 1; d < 16; d <<= 1) ps += __shfl_xor(ps, d);
        const float corr = (m_old > 0.5f * NEG_INF) ? __expf(m_old - m_new) : 0.0f;
        if (c0 == 0) {
          m_s[r]    = m_new;
          l_s[r]    = l_s[r] * corr + ps;
          corr_s[r] = corr;
        }
        Pq[r][c0]      = (_Float16)p0;
        Pq[r][c0 + 16] = (_Float16)p1;
      }
      BAR_LDS();   // (B) Pq/corr ready — vmcnt NOT drained

      // ---- PV: rescale O, 16 MFMA with tr_read B-frags ----
      {
#pragma unroll
        for (int rt = 0; rt < 2; ++rt)
#pragma unroll
          for (int j = 0; j < 4; ++j) {
            const float cr = corr_s[rt * 16 + lg * 4 + j];
#pragma unroll
            for (int ct = 0; ct < 8; ++ct) oacc[rt][ct][j] *= cr;
          }
        half8 a0 = *(const half8*)&Pq[lr][lg * 8];
        half8 a1 = *(const half8*)&Pq[16 + lr][lg * 8];
        half4v lo[8], hi[8];
        const uint32_t ab =
            (uint32_t)(uintptr_t)(void*)&Kbuf[cur][w * 4096 + l * 4];  // +l*8 bytes
#define TRRD(CT, O0, O1)                                                      \
        asm volatile("ds_read_b64_tr_b16 %0, %2 offset:" O0 "\n\t"            \
                     "ds_read_b64_tr_b16 %1, %2 offset:" O1                   \
                     : "=v"(lo[CT]), "=v"(hi[CT]) : "v"(ab));
        TRRD(0, "0",    "512")  TRRD(1, "1024", "1536")
        TRRD(2, "2048", "2560") TRRD(3, "3072", "3584")
        TRRD(4, "4096", "4608") TRRD(5, "5120", "5632")
        TRRD(6, "6144", "6656") TRRD(7, "7168", "7680")
#undef TRRD
        asm volatile("s_waitcnt lgkmcnt(0)" ::: "memory");
        __builtin_amdgcn_sched_barrier(0);
#pragma unroll
        for (int ct = 0; ct < 8; ++ct) {
          half8 bf = __builtin_shufflevector(lo[ct], hi[ct], 0, 1, 2, 3, 4, 5, 6, 7);
          oacc[0][ct] = mfma16(a0, bf, oacc[0][ct]);
          oacc[1][ct] = mfma16(a1, bf, oacc[1][ct]);
        }
      }
      __syncthreads();   // (C) full drain: Kbuf[cur] free, old staging complete

      // ---- stage tile kt+2 into buf[cur] ----
      if (kt + 2 < nkt) {
        if constexpr (WS) {
          const _Float16* tn = wsx + (size_t)(b * 64 + kt + 2) * 32768;
#pragma unroll
          for (int i = 0; i < 8; ++i)
            __builtin_amdgcn_global_load_lds(
                (const __attribute__((address_space(1))) void*)(tn + w * 4096 + i * 512 + l * 8),
                (__attribute__((address_space(3))) void*)(&Kbuf[cur][w * 4096 + i * 512]), 16, 0, 0);
        } else {
          const int skey = tid >> 4, sc = tid & 15;
          const float* kp = xb + (size_t)((kt + 2) * 32 + skey) * DN + sc * 4;
#pragma unroll
          for (int j = 0; j < 16; ++j) {
            const int f = sc * 4 + 64 * j;
            float4 v = *(const float4*)(kp + 64 * j);
            half4v h = {(_Float16)v.x, (_Float16)v.y, (_Float16)v.z, (_Float16)v.w};
            *(half4v*)&Kbuf[cur][img_off(skey, f)] = h;
          }
        }
      }
    }

    // ---- epilogue: per-row <x,O>, |x|^2, |O|^2 ----
    {
      float* ered = &Sred[0][0][0];
#pragma unroll
      for (int rt = 0; rt < 2; ++rt)
#pragma unroll
        for (int j = 0; j < 4; ++j) {
          const int row = rt * 16 + lg * 4 + j;
          const float* xr = xb + (size_t)(qbase + row) * DN + w * 128 + lr;
          float a1 = 0.f, a2 = 0.f, a3 = 0.f;
#pragma unroll
          for (int ct = 0; ct < 8; ++ct) {
            const float xv = xr[ct * 16];
            const float ov = oacc[rt][ct][j];
            a1 += xv * ov; a2 += xv * xv; a3 += ov * ov;
          }
#pragma unroll
          for (int d = 1; d < 16; d <<= 1) {
            a1 += __shfl_xor(a1, d);
            a2 += __shfl_xor(a2, d);
            a3 += __shfl_xor(a3, d);
          }
          if (lr == 0) {
            float* e = ered + (row * 8 + w) * 4;
            e[0] = a1; e[1] = a2; e[2] = a3;
          }
        }
    }
    __syncthreads();
    if (tid < 32) {
      const float* ered = &Sred[0][0][0];
      float SxO = 0.f, Sxx = 0.f, SOO = 0.f;
#pragma unroll
      for (int wv = 0; wv < 8; ++wv) {
        const float* e = ered + (tid * 8 + wv) * 4;
        SxO += e[0]; Sxx += e[1]; SOO += e[2];
      }
      const float lden = l_s[tid];
      float cosv = 0.0f;
      if (lden > 0.0f) {
        const float nx = fmaxf(sqrtf(Sxx), 1e-12f);
        const float nc = fmaxf(sqrtf(SOO) / lden, 1e-12f);
        cosv = (SxO / lden) / (nx * nc);
      }
      float nov = fminf(fmaxf(1.0f - cosv, 0.0f), 2.0f) * 0.5f;
      gate_s[tid] = 1.0f + alpha * tanhf(sigma * nov);
    }
    __syncthreads();
    {
#pragma unroll
      for (int rt = 0; rt < 2; ++rt)
#pragma unroll
        for (int j = 0; j < 4; ++j) {
          const int row = rt * 16 + lg * 4 + j;
          const float g = gate_s[row];
          const float* xr = xb + (size_t)(qbase + row) * DN + w * 128 + lr;
          float* orow     = ob + (size_t)(qbase + row) * DN + w * 128 + lr;
#pragma unroll
          for (int ct = 0; ct < 8; ++ct) {
            const float z = xr[ct * 16] * g;
            const float u = 0.7978845608028654f * (z + 0.044715f * z * z * z);
            orow[ct * 16] = 0.5f * z * (1.0f + tanhf(u));
          }
        }
    }
    __syncthreads();
  }
}

extern "C" void kernel_launch(void* const* d_in, const int* in_sizes, int n_in,
                              void* d_out, int out_size, void* d_ws, size_t ws_size,
                              hipStream_t stream) {
  const float* x  = (const float*)d_in[0];
  const float* la = (const float*)d_in[1];
  const float* ls = (const float*)d_in[2];
  float* out = (float*)d_out;
  const size_t need = (size_t)8 * 64 * 32768 * 2;   // 32 MB f16 tile images
  if (ws_size >= need) {
    convert_x<<<dim3(8192), dim3(256), 0, stream>>>(x, (_Float16*)d_ws);
    attn_gate<true><<<dim3(256), dim3(512), 0, stream>>>(
        x, (const _Float16*)d_ws, la, ls, out);
  } else {
    attn_gate<false><<<dim3(256), dim3(512), 0, stream>>>(
        x, (const _Float16*)nullptr, la, ls, out);
  }
}